// Round 4
// baseline (95.955 us; speedup 1.0000x reference)
//
#include <hip/hip_runtime.h>
#include <hip/hip_bf16.h>
#include <math.h>

// ChoiceRNN collapses to a constant:
//   log_softmax of a length-1 vector == 0 exactly  =>  all scan activations == 0
//   final log_softmax(zeros(C)) == -log(C) for every element, C = 32768.
// Reference output dtype is FLOAT32 (round-2 post-mortem: absmax 10.375 decoded
// as "second half of a 128 KiB f32 buffer left at zero"), so this is a
// 128 KiB f32 constant fill of -log(32768) = -10.397208.

__global__ void ChoiceRNN_fill_f32x4(float4* out, int n_vec4, float v) {
    int i = blockIdx.x * blockDim.x + threadIdx.x;
    if (i < n_vec4) {
        out[i] = make_float4(v, v, v, v);
    }
}

__global__ void ChoiceRNN_fill_f32_tail(float* out, int start, int n, float v) {
    int i = blockIdx.x * blockDim.x + threadIdx.x;
    if (i < n) out[start + i] = v;
}

extern "C" void kernel_launch(void* const* d_in, const int* in_sizes, int n_in,
                              void* d_out, int out_size, void* d_ws, size_t ws_size,
                              hipStream_t stream) {
    (void)d_in; (void)in_sizes; (void)n_in; (void)d_ws; (void)ws_size;

    // value = -log(C) with C = out_size (32768 for this problem)
    float v = -logf((float)out_size);

    int n_vec4 = out_size / 4;            // 4 f32 per float4 (16 B per lane)
    int tail_start = n_vec4 * 4;
    int tail_n = out_size - tail_start;   // 0 at out_size = 32768

    if (n_vec4 > 0) {
        int block = 256;
        int grid = (n_vec4 + block - 1) / block;  // 32 blocks at out_size=32768
        ChoiceRNN_fill_f32x4<<<grid, block, 0, stream>>>((float4*)d_out, n_vec4, v);
    }
    if (tail_n > 0) {
        ChoiceRNN_fill_f32_tail<<<1, 64, 0, stream>>>((float*)d_out, tail_start, tail_n, v);
    }
}